// Round 2
// baseline (218.764 us; speedup 1.0000x reference)
//
#include <hip/hip_runtime.h>

#define LAMBDA_COORD 5.0f
#define LAMBDA_NOOBJ 0.5f

// N*S*S = 802816 cells; preds 30 f32/cell, targets 25 f32/cell.
// Key facts: 2 pred cells = 15 float4 (so lane parity determines a constant
// register offset 0/2); 4 target cells = 25 float4 (lane&3 -> offset 0..3).
// Every lane loads its whole cell into registers with 16B-aligned dwordx4,
// wave-dense coverage, NO LDS, NO staging barriers.

__global__ void zero_out_kernel(float* out, int n) {
    int i = blockIdx.x * blockDim.x + threadIdx.x;
    if (i < n) out[i] = 0.0f;
}

__global__ __launch_bounds__(256, 4) void yolo_loss_kernel(
    const float* __restrict__ preds, const float* __restrict__ targets,
    float* __restrict__ out, int n_cells)
{
    __shared__ float s_part[4];
    const int tid = threadIdx.x;
    const int c = blockIdx.x * 256 + tid;

    float loss = 0.0f;
    if (c < n_cells) {
        const float4* __restrict__ p4 = (const float4*)preds;
        const float4* __restrict__ t4 = (const float4*)targets;

        // ---- preds: 8 aligned float4 covering this cell (+0 or +2 offset) ----
        alignas(16) float Pf[32];
        {
            const int pi = 15 * (c >> 1) + 7 * (c & 1);
            #pragma unroll
            for (int k = 0; k < 8; ++k)
                *(float4*)&Pf[4 * k] = p4[pi + k];
        }
        // ---- targets: 7 aligned float4 covering this cell (+r offset) ----
        alignas(16) float Tf[28];
        {
            const int ti = 25 * (c >> 2) + 6 * (c & 3);
            #pragma unroll
            for (int k = 0; k < 7; ++k)
                *(float4*)&Tf[4 * k] = t4[ti + k];
        }

        const bool podd = (c & 1);
        const int r = c & 3;
        const bool r1 = r & 1, r2 = (r & 2) != 0;

        // constant-index register selects (SROA keeps Pf/Tf in VGPRs)
        auto selp = [&](int k) { return podd ? Pf[k + 2] : Pf[k]; };
        auto selt = [&](int k) {
            float a = r1 ? Tf[k + 1] : Tf[k];
            float b = r1 ? Tf[k + 3] : Tf[k + 2];
            return r2 ? b : a;
        };

        float p0 = selp(0), p5 = selp(5);
        // jnp.argmax picks first index on tie -> box1 only on strict greater.
        bool pick1 = p5 > p0;
        float b0 = pick1 ? p5 : p0;
        float b1 = pick1 ? selp(6) : selp(1);
        float b2 = pick1 ? selp(7) : selp(2);
        float b3 = pick1 ? selp(8) : selp(3);
        float b4 = pick1 ? selp(9) : selp(4);

        float t0 = selt(0);
        float d1 = b1 - selt(1), d2 = b2 - selt(2);
        float d3 = b3 - selt(3), d4 = b4 - selt(4);
        float box_loss = d1 * d1 + d2 * d2 + d3 * d3 + d4 * d4;
        float dpc = b0 - t0;
        float pc_loss = dpc * dpc;

        float class_loss = 0.0f;
        #pragma unroll
        for (int j = 0; j < 20; ++j) {
            float d = selp(10 + j) - selt(5 + j);
            class_loss += d * d;
        }

        float obj_term = LAMBDA_COORD * box_loss + pc_loss + class_loss;
        float noobj_term = LAMBDA_NOOBJ * (p0 * p0 + p5 * p5);
        loss = (t0 == 1.0f) ? obj_term : noobj_term;
    }

    // wave (64-lane) shuffle reduction
    #pragma unroll
    for (int off = 32; off > 0; off >>= 1)
        loss += __shfl_down(loss, off, 64);

    const int wave = tid >> 6;
    if ((tid & 63) == 0) s_part[wave] = loss;
    __syncthreads();
    if (tid == 0) {
        float s = s_part[0] + s_part[1] + s_part[2] + s_part[3];
        atomicAdd(out, s);
    }
}

extern "C" void kernel_launch(void* const* d_in, const int* in_sizes, int n_in,
                              void* d_out, int out_size, void* d_ws, size_t ws_size,
                              hipStream_t stream) {
    const float* preds   = (const float*)d_in[0];
    const float* targets = (const float*)d_in[1];
    float* out = (float*)d_out;

    const int n_cells = in_sizes[0] / 30;   // 802816 (multiple of 256)

    // d_out is poisoned (0xAA) before every timed replay — zero it on-stream.
    zero_out_kernel<<<(out_size + 255) / 256, 256, 0, stream>>>(out, out_size);

    const int grid = (n_cells + 255) / 256; // 3136
    yolo_loss_kernel<<<grid, 256, 0, stream>>>(preds, targets, out, n_cells);
}

// Round 3
// 193.637 us; speedup vs baseline: 1.1298x; 1.1298x over previous
//
#include <hip/hip_runtime.h>

#define LAMBDA_COORD 5.0f
#define LAMBDA_NOOBJ 0.5f

// 802816 cells; preds 30 f32/cell (120 B), targets 25 f32/cell (100 B).
// Each lane loads its whole cell with dword-aligned wide loads (gfx950
// global_load_dwordx4 needs only 4 B alignment). Values live in NAMED
// ext-vector variables -> SROA-proof, zero scratch, zero select ALU.

typedef float f4u __attribute__((ext_vector_type(4), aligned(4)));
typedef float f2u __attribute__((ext_vector_type(2), aligned(4)));

__global__ void zero_out_kernel(float* out, int n) {
    int i = blockIdx.x * blockDim.x + threadIdx.x;
    if (i < n) out[i] = 0.0f;
}

__global__ __launch_bounds__(256, 6) void yolo_loss_kernel(
    const float* __restrict__ preds, const float* __restrict__ targets,
    float* __restrict__ out, int n_cells)
{
    __shared__ float s_part[4];
    const int tid = threadIdx.x;
    const int c = blockIdx.x * 256 + tid;

    float loss = 0.0f;
    if (c < n_cells) {
        const float* pbase = preds + (size_t)c * 30;
        const float* tbase = targets + (size_t)c * 25;
        const f4u* pp = (const f4u*)pbase;
        const f4u* tp = (const f4u*)tbase;

        // preds p[0..29]
        f4u P0 = pp[0], P1 = pp[1], P2 = pp[2], P3 = pp[3];
        f4u P4 = pp[4], P5 = pp[5], P6 = pp[6];
        f2u P7 = *(const f2u*)(pbase + 28);
        // targets t[0..24]
        f4u T0 = tp[0], T1 = tp[1], T2 = tp[2], T3 = tp[3];
        f4u T4 = tp[4], T5 = tp[5];
        float t24 = tbase[24];

        // box confidences: p[0], p[5]
        float p0 = P0.x, p5c = P1.y;
        // jnp.argmax picks first index on tie -> box1 only on strict greater.
        bool pick1 = p5c > p0;
        float b0 = pick1 ? p5c  : p0;
        float b1 = pick1 ? P1.z : P0.y;   // p[6] : p[1]
        float b2 = pick1 ? P1.w : P0.z;   // p[7] : p[2]
        float b3 = pick1 ? P2.x : P0.w;   // p[8] : p[3]
        float b4 = pick1 ? P2.y : P1.x;   // p[9] : p[4]

        float t0 = T0.x;
        float d1 = b1 - T0.y, d2 = b2 - T0.z, d3 = b3 - T0.w, d4 = b4 - T1.x;
        float box_loss = d1 * d1 + d2 * d2 + d3 * d3 + d4 * d4;
        float dpc = b0 - t0;
        float pc_loss = dpc * dpc;

        // classes: p[10..29] vs t[5..24]
        float cl = 0.0f, d;
        d = P2.z - T1.y; cl += d * d;
        d = P2.w - T1.z; cl += d * d;
        d = P3.x - T1.w; cl += d * d;
        d = P3.y - T2.x; cl += d * d;
        d = P3.z - T2.y; cl += d * d;
        d = P3.w - T2.z; cl += d * d;
        d = P4.x - T2.w; cl += d * d;
        d = P4.y - T3.x; cl += d * d;
        d = P4.z - T3.y; cl += d * d;
        d = P4.w - T3.z; cl += d * d;
        d = P5.x - T3.w; cl += d * d;
        d = P5.y - T4.x; cl += d * d;
        d = P5.z - T4.y; cl += d * d;
        d = P5.w - T4.z; cl += d * d;
        d = P6.x - T4.w; cl += d * d;
        d = P6.y - T5.x; cl += d * d;
        d = P6.z - T5.y; cl += d * d;
        d = P6.w - T5.z; cl += d * d;
        d = P7.x - T5.w; cl += d * d;
        d = P7.y - t24;  cl += d * d;

        float obj_term = LAMBDA_COORD * box_loss + pc_loss + cl;
        float noobj_term = LAMBDA_NOOBJ * (p0 * p0 + p5c * p5c);
        loss = (t0 == 1.0f) ? obj_term : noobj_term;
    }

    // wave (64-lane) shuffle reduction
    #pragma unroll
    for (int off = 32; off > 0; off >>= 1)
        loss += __shfl_down(loss, off, 64);

    const int wave = tid >> 6;
    if ((tid & 63) == 0) s_part[wave] = loss;
    __syncthreads();
    if (tid == 0) {
        float s = s_part[0] + s_part[1] + s_part[2] + s_part[3];
        atomicAdd(out, s);
    }
}

extern "C" void kernel_launch(void* const* d_in, const int* in_sizes, int n_in,
                              void* d_out, int out_size, void* d_ws, size_t ws_size,
                              hipStream_t stream) {
    const float* preds   = (const float*)d_in[0];
    const float* targets = (const float*)d_in[1];
    float* out = (float*)d_out;

    const int n_cells = in_sizes[0] / 30;   // 802816 (multiple of 256)

    // d_out is poisoned (0xAA) before every timed replay — zero it on-stream.
    zero_out_kernel<<<(out_size + 255) / 256, 256, 0, stream>>>(out, out_size);

    const int grid = (n_cells + 255) / 256; // 3136
    yolo_loss_kernel<<<grid, 256, 0, stream>>>(preds, targets, out, n_cells);
}